// Round 14
// baseline (48.807 us; speedup 1.0000x reference)
//
#include <hip/hip_runtime.h>

#define N_IN   4096
#define N_OUT  4082      // 4096 - 15 + 1
#define KS     15
#define TM     128       // output rows per block (2 chunks x 64)
#define TN     128       // output cols per block
#define CH     64        // output rows per chunk (4 row-groups x 16)
#define PR     142       // patch rows staged (TM + KS - 1)
#define PC     144       // patch cols staged (TN + 16)
#define PCB    (PC * 2)  // patch row pitch in bytes = 288
#define C4R    36        // float4 chunks per patch row (PC/4)
#define PITEMS (78 * C4R)          // prologue items (rows [0,78)) = 2808
#define CITEMS (CH * C4R)          // chunk-0 staging items (rows [78,142)) = 2304

// R14 = R13 + __launch_bounds__(512, 8). The R9-R13 ~36-40us plateau with no
// pipe >35% busy was latency-bound at 16 waves/CU: (512,4) = 4 waves/EU =
// 2 blocks/CU cap carried since R2. Now 8 waves/EU = 4 blocks/CU = 32 waves.
// LDS 40,896 B x 4 = 163,584 <= 160 KiB (just fits). R13 measured VGPR=48
// <= 64 needed for 8 waves/SIMD (m69) -> no spill expected.
// B-table in GLOBAL d_ws (pre-kernel); LDS = patch only; 2 barriers/block;
// shared-window pairing: 5 A-reads + 2 B-loads feed 8 MFMAs.
// Spill gauge: WRITE_SIZE - 66.6 MB ~ 0. Bank: pitch 144 bf16 = 72 words
// == 8 mod 32 -> verified conflict-free b128 pattern (0 conflicts measured).

typedef __attribute__((ext_vector_type(8))) short bf16x8;
typedef __attribute__((ext_vector_type(4))) float f32x4;

__device__ inline unsigned short f2bf(float f) {   // round-to-nearest-even
    unsigned u = __builtin_bit_cast(unsigned, f);
    u += 0x7FFFu + ((u >> 16) & 1u);
    return (unsigned short)(u >> 16);
}
__device__ inline ushort4 f2bf4(float4 v) {
    ushort4 b; b.x = f2bf(v.x); b.y = f2bf(v.y); b.z = f2bf(v.z); b.w = f2bf(v.w);
    return b;
}

// load one staging item (patch row = base + it/C4R) into v, zero-padded
#define ISSUE_ITEM(base, it, v) {                                         \
    const int _row = (base) + (it) / C4R;                                 \
    const int _c4  = (it) % C4R;                                          \
    const int _gr  = r0 + _row;                                           \
    const int _gc  = c0 + _c4 * 4;                                        \
    if (_gr < N_IN && _gc < N_IN)                                         \
        v = *reinterpret_cast<const float4*>(&x[_gr * N_IN + _gc]);       \
}
// convert + write item into the patch buffer
#define COMMIT_ITEM(base, it, v) {                                        \
    const int _row = (base) + (it) / C4R;                                 \
    const int _c4  = (it) % C4R;                                          \
    *reinterpret_cast<ushort4*>(&xs[_row * PC + _c4 * 4]) = f2bf4(v);     \
}

#define MF(a, b, c) __builtin_amdgcn_mfma_f32_16x16x32_bf16((a), (b), (c), 0, 0, 0)

// ---- pre-kernel: build the 16-entry B table in global ws ----
// entry idx = P*2+h: B[k=16p'+q'][n=m] = wpad[2P+p'][q' + 16h - m]
__global__ __launch_bounds__(64) void btab_fill_kernel(
    const float* __restrict__ w, unsigned short* __restrict__ bt)
{
    const int idx  = blockIdx.x;          // 0..15
    const int lane = threadIdx.x;         // 0..63
    const int P  = idx >> 1, h = idx & 1;
    const int m  = lane & 15;
    const int g  = lane >> 4;
    const int gp = g >> 1, g1 = g & 1;
    bf16x8 f;
    #pragma unroll
    for (int e = 0; e < 8; ++e) {
        const int prow = 2 * P + gp;
        const int col  = g1 * 8 + e + 16 * h - m;
        const float vv = (prow < KS && col >= 0 && col < KS) ? w[prow * KS + col] : 0.f;
        f[e] = (short)f2bf(vv);
    }
    *reinterpret_cast<bf16x8*>(&bt[idx * 512 + lane * 8]) = f;
}

__global__ __launch_bounds__(512, 8) void Conv2DScratch_82025285419642_kernel(
    const float* __restrict__ x, const unsigned short* __restrict__ btab,
    const float* __restrict__ bias, float* __restrict__ out)
{
    __shared__ unsigned short xs[PR * PC];   // 40,896 B; x4 blocks = 160 KiB

    const int tid  = threadIdx.x;
    const int lane = tid & 63;
    const int wv   = tid >> 6;
    const int m    = lane & 15;           // A row within band / D col
    const int g    = lane >> 4;           // k-group / D row group
    const int gp   = g >> 1;              // p' within pair
    const int g1   = g & 1;               // q' high/low 8
    const int wr   = wv >> 1;             // row-group: rows [64c+16wr, +16)
    const int wc   = wv & 1;              // col-group: cols [64wc, 64wc+64)

    // bijective XCD-chunked block swizzle (1024 blocks, 8 XCDs, 128 each)
    const int bid = blockIdx.x;
    const int s   = ((bid & 7) << 7) | (bid >> 3);
    const int c0  = (s & 31) * TN;        // output col base
    const int r0  = (s >> 5) * TM;        // output row base

    // ---- prologue: stage patch rows [0,78) ----
    float4 p0 = make_float4(0.f,0.f,0.f,0.f), p1 = p0, p2 = p0,
           p3 = p0, p4 = p0, p5 = p0;
    ISSUE_ITEM(0, tid,        p0);
    ISSUE_ITEM(0, tid +  512, p1);
    ISSUE_ITEM(0, tid + 1024, p2);
    ISSUE_ITEM(0, tid + 1536, p3);
    ISSUE_ITEM(0, tid + 2048, p4);
    if (tid < PITEMS - 2560) ISSUE_ITEM(0, tid + 2560, p5);   // 248 tail
    const float b0 = bias[0];
    COMMIT_ITEM(0, tid,        p0);
    COMMIT_ITEM(0, tid +  512, p1);
    COMMIT_ITEM(0, tid + 1024, p2);
    COMMIT_ITEM(0, tid + 1536, p3);
    COMMIT_ITEM(0, tid + 2048, p4);
    if (tid < PITEMS - 2560) COMMIT_ITEM(0, tid + 2560, p5);
    __syncthreads();

    const unsigned char* xsb = (const unsigned char*)xs;
    const unsigned char* btb = (const unsigned char*)btab;
    const int cb0    = 128 * wc + 16 * g1;   // A-read byte offset within row
    const int lane16 = lane * 16;

    // one pair-step: 5 shared A-windows (LDS) + 2 B-frags (global, L1-hot)
    #define PPAIR(ROW) {                                                  \
        const unsigned char* _ab = xsb + (ROW) * PCB + cb0;               \
        const bf16x8 a0 = *reinterpret_cast<const bf16x8*>(_ab +   0);    \
        const bf16x8 a1 = *reinterpret_cast<const bf16x8*>(_ab +  32);    \
        const bf16x8 a2 = *reinterpret_cast<const bf16x8*>(_ab +  64);    \
        const bf16x8 a3 = *reinterpret_cast<const bf16x8*>(_ab +  96);    \
        const bf16x8 a4 = *reinterpret_cast<const bf16x8*>(_ab + 128);    \
        const bf16x8 bl = *reinterpret_cast<const bf16x8*>(                \
            btb + _Pb * 2048 + lane16);                                   \
        const bf16x8 bh = *reinterpret_cast<const bf16x8*>(                \
            btb + _Pb * 2048 + 1024 + lane16);                            \
        acc0 = MF(a0, bl, acc0); acc0 = MF(a1, bh, acc0);                 \
        acc1 = MF(a1, bl, acc1); acc1 = MF(a2, bh, acc1);                 \
        acc2 = MF(a2, bl, acc2); acc2 = MF(a3, bh, acc2);                 \
        acc3 = MF(a3, bl, acc3); acc3 = MF(a4, bh, acc3);                 \
    }

    #define DO_CHUNK(CBASE)                                               \
        f32x4 acc0 = {0.f,0.f,0.f,0.f}, acc1 = acc0, acc2 = acc0, acc3 = acc0; \
        const int rbg = (CBASE) + 16 * wr + m + gp;                       \
        const int rb7 = (CBASE) + 16 * wr + m + 14;                       \
        { const int _Pb = 0; PPAIR(rbg +  0) }                            \
        { const int _Pb = 1; PPAIR(rbg +  2) }                            \
        { const int _Pb = 2; PPAIR(rbg +  4) }                            \
        { const int _Pb = 3; PPAIR(rbg +  6) }                            \
        { const int _Pb = 4; PPAIR(rbg +  8) }                            \
        { const int _Pb = 5; PPAIR(rbg + 10) }                            \
        { const int _Pb = 6; PPAIR(rbg + 12) }                            \
        { const int _Pb = 7; PPAIR(rb7) }                                 \
        const int ocb = c0 + 64 * wc + m;                                 \
        const int or0 = r0 + (CBASE) + 16 * wr + g * 4;                   \
        { STORE_TILE(0, acc0) STORE_TILE(1, acc1)                         \
          STORE_TILE(2, acc2) STORE_TILE(3, acc3) }

    #define STORE_TILE(t, a) {                                            \
        const int _oc = ocb + (t) * 16;                                   \
        if (_oc < N_OUT) {                                                \
            _Pragma("unroll")                                             \
            for (int r = 0; r < 4; ++r) {                                 \
                if (or0 + r < N_OUT)                                      \
                    out[(or0 + r) * N_OUT + _oc] = a[r] + b0;             \
            }                                                             \
        }                                                                 \
    }

    // ---- chunk 0: compute rows [0,64); stage rows [78,142) underneath ----
    {
        float4 s0 = make_float4(0.f,0.f,0.f,0.f), s1 = s0, s2 = s0, s3 = s0, s4 = s0;
        ISSUE_ITEM(78, tid,        s0);
        ISSUE_ITEM(78, tid +  512, s1);
        ISSUE_ITEM(78, tid + 1024, s2);
        ISSUE_ITEM(78, tid + 1536, s3);
        if (tid < CITEMS - 2048) ISSUE_ITEM(78, tid + 2048, s4);   // 256 tail

        DO_CHUNK(0)

        COMMIT_ITEM(78, tid,        s0);
        COMMIT_ITEM(78, tid +  512, s1);
        COMMIT_ITEM(78, tid + 1024, s2);
        COMMIT_ITEM(78, tid + 1536, s3);
        if (tid < CITEMS - 2048) COMMIT_ITEM(78, tid + 2048, s4);
        __syncthreads();
    }
    // ---- chunk 1: compute rows [64,128) ----
    {
        DO_CHUNK(64)
    }
    #undef PPAIR
    #undef DO_CHUNK
    #undef STORE_TILE
}

extern "C" void kernel_launch(void* const* d_in, const int* in_sizes, int n_in,
                              void* d_out, int out_size, void* d_ws, size_t ws_size,
                              hipStream_t stream) {
    const float* x    = (const float*)d_in[0];
    const float* w    = (const float*)d_in[1];
    const float* bias = (const float*)d_in[2];
    float* out        = (float*)d_out;
    unsigned short* bt = (unsigned short*)d_ws;     // 16 KB B-table

    btab_fill_kernel<<<dim3(16), dim3(64), 0, stream>>>(w, bt);

    dim3 block(512);
    dim3 grid(32 * 32);   // 1024 blocks, swizzled in-kernel; 4/CU
    Conv2DScratch_82025285419642_kernel<<<grid, block, 0, stream>>>(
        x, bt, bias, out);
}

// Round 15
// 47.869 us; speedup vs baseline: 1.0196x; 1.0196x over previous
//
#include <hip/hip_runtime.h>

#define N_IN   4096
#define N_OUT  4082      // 4096 - 15 + 1
#define KS     15
#define TM     128       // output rows per block (2 chunks x 64)
#define TN     128       // output cols per block
#define CH     64        // output rows per chunk (4 row-groups x 16)
#define PR     142       // patch rows staged (TM + KS - 1)
#define PC     144       // patch cols staged (TN + 16)
#define PCB    (PC * 2)  // patch row pitch in bytes = 288
#define C4R    36        // float4 chunks per patch row (PC/4)
#define PITEMS (78 * C4R)          // prologue items (rows [0,78)) = 2808
#define CITEMS (CH * C4R)          // chunk-0 staging items (rows [78,142)) = 2304

// R15 = R13 + __launch_bounds__(512, 6). Measured tradeoff:
//   (512,4): 2 blk/CU, VGPR 48, 40.6us  — occupancy-capped
//   (512,8): 4 blk/CU, VGPR 32, 48.8us  — register-starved (staging serialized)
//   (512,6): 3 blk/CU, VGPR budget ~85 >= demand ~48-56 -> TLP x1.5, same code
// LDS 40,896 x 3 = 122.7 KB <= 160 KiB. Guard: VGPR_Count must NOT drop to ~32.
// B-table in GLOBAL d_ws (pre-kernel); LDS = patch only; 2 barriers/block;
// shared-window pairing: 5 A-reads + 2 B-loads feed 8 MFMAs.
// Spill gauge: WRITE_SIZE - 66.6 MB ~ 0. Bank: pitch 144 bf16 = 72 words
// == 8 mod 32 -> verified conflict-free b128 pattern (0 conflicts measured).

typedef __attribute__((ext_vector_type(8))) short bf16x8;
typedef __attribute__((ext_vector_type(4))) float f32x4;

__device__ inline unsigned short f2bf(float f) {   // round-to-nearest-even
    unsigned u = __builtin_bit_cast(unsigned, f);
    u += 0x7FFFu + ((u >> 16) & 1u);
    return (unsigned short)(u >> 16);
}
__device__ inline ushort4 f2bf4(float4 v) {
    ushort4 b; b.x = f2bf(v.x); b.y = f2bf(v.y); b.z = f2bf(v.z); b.w = f2bf(v.w);
    return b;
}

// load one staging item (patch row = base + it/C4R) into v, zero-padded
#define ISSUE_ITEM(base, it, v) {                                         \
    const int _row = (base) + (it) / C4R;                                 \
    const int _c4  = (it) % C4R;                                          \
    const int _gr  = r0 + _row;                                           \
    const int _gc  = c0 + _c4 * 4;                                        \
    if (_gr < N_IN && _gc < N_IN)                                         \
        v = *reinterpret_cast<const float4*>(&x[_gr * N_IN + _gc]);       \
}
// convert + write item into the patch buffer
#define COMMIT_ITEM(base, it, v) {                                        \
    const int _row = (base) + (it) / C4R;                                 \
    const int _c4  = (it) % C4R;                                          \
    *reinterpret_cast<ushort4*>(&xs[_row * PC + _c4 * 4]) = f2bf4(v);     \
}

#define MF(a, b, c) __builtin_amdgcn_mfma_f32_16x16x32_bf16((a), (b), (c), 0, 0, 0)

// ---- pre-kernel: build the 16-entry B table in global ws ----
// entry idx = P*2+h: B[k=16p'+q'][n=m] = wpad[2P+p'][q' + 16h - m]
__global__ __launch_bounds__(64) void btab_fill_kernel(
    const float* __restrict__ w, unsigned short* __restrict__ bt)
{
    const int idx  = blockIdx.x;          // 0..15
    const int lane = threadIdx.x;         // 0..63
    const int P  = idx >> 1, h = idx & 1;
    const int m  = lane & 15;
    const int g  = lane >> 4;
    const int gp = g >> 1, g1 = g & 1;
    bf16x8 f;
    #pragma unroll
    for (int e = 0; e < 8; ++e) {
        const int prow = 2 * P + gp;
        const int col  = g1 * 8 + e + 16 * h - m;
        const float vv = (prow < KS && col >= 0 && col < KS) ? w[prow * KS + col] : 0.f;
        f[e] = (short)f2bf(vv);
    }
    *reinterpret_cast<bf16x8*>(&bt[idx * 512 + lane * 8]) = f;
}

__global__ __launch_bounds__(512, 6) void Conv2DScratch_82025285419642_kernel(
    const float* __restrict__ x, const unsigned short* __restrict__ btab,
    const float* __restrict__ bias, float* __restrict__ out)
{
    __shared__ unsigned short xs[PR * PC];   // 40,896 B; x3 blocks = 122.7 KiB

    const int tid  = threadIdx.x;
    const int lane = tid & 63;
    const int wv   = tid >> 6;
    const int m    = lane & 15;           // A row within band / D col
    const int g    = lane >> 4;           // k-group / D row group
    const int gp   = g >> 1;              // p' within pair
    const int g1   = g & 1;               // q' high/low 8
    const int wr   = wv >> 1;             // row-group: rows [64c+16wr, +16)
    const int wc   = wv & 1;              // col-group: cols [64wc, 64wc+64)

    // bijective XCD-chunked block swizzle (1024 blocks, 8 XCDs, 128 each)
    const int bid = blockIdx.x;
    const int s   = ((bid & 7) << 7) | (bid >> 3);
    const int c0  = (s & 31) * TN;        // output col base
    const int r0  = (s >> 5) * TM;        // output row base

    // ---- prologue: stage patch rows [0,78) ----
    float4 p0 = make_float4(0.f,0.f,0.f,0.f), p1 = p0, p2 = p0,
           p3 = p0, p4 = p0, p5 = p0;
    ISSUE_ITEM(0, tid,        p0);
    ISSUE_ITEM(0, tid +  512, p1);
    ISSUE_ITEM(0, tid + 1024, p2);
    ISSUE_ITEM(0, tid + 1536, p3);
    ISSUE_ITEM(0, tid + 2048, p4);
    if (tid < PITEMS - 2560) ISSUE_ITEM(0, tid + 2560, p5);   // 248 tail
    const float b0 = bias[0];
    COMMIT_ITEM(0, tid,        p0);
    COMMIT_ITEM(0, tid +  512, p1);
    COMMIT_ITEM(0, tid + 1024, p2);
    COMMIT_ITEM(0, tid + 1536, p3);
    COMMIT_ITEM(0, tid + 2048, p4);
    if (tid < PITEMS - 2560) COMMIT_ITEM(0, tid + 2560, p5);
    __syncthreads();

    const unsigned char* xsb = (const unsigned char*)xs;
    const unsigned char* btb = (const unsigned char*)btab;
    const int cb0    = 128 * wc + 16 * g1;   // A-read byte offset within row
    const int lane16 = lane * 16;

    // one pair-step: 5 shared A-windows (LDS) + 2 B-frags (global, L1-hot)
    #define PPAIR(ROW) {                                                  \
        const unsigned char* _ab = xsb + (ROW) * PCB + cb0;               \
        const bf16x8 a0 = *reinterpret_cast<const bf16x8*>(_ab +   0);    \
        const bf16x8 a1 = *reinterpret_cast<const bf16x8*>(_ab +  32);    \
        const bf16x8 a2 = *reinterpret_cast<const bf16x8*>(_ab +  64);    \
        const bf16x8 a3 = *reinterpret_cast<const bf16x8*>(_ab +  96);    \
        const bf16x8 a4 = *reinterpret_cast<const bf16x8*>(_ab + 128);    \
        const bf16x8 bl = *reinterpret_cast<const bf16x8*>(                \
            btb + _Pb * 2048 + lane16);                                   \
        const bf16x8 bh = *reinterpret_cast<const bf16x8*>(                \
            btb + _Pb * 2048 + 1024 + lane16);                            \
        acc0 = MF(a0, bl, acc0); acc0 = MF(a1, bh, acc0);                 \
        acc1 = MF(a1, bl, acc1); acc1 = MF(a2, bh, acc1);                 \
        acc2 = MF(a2, bl, acc2); acc2 = MF(a3, bh, acc2);                 \
        acc3 = MF(a3, bl, acc3); acc3 = MF(a4, bh, acc3);                 \
    }

    #define DO_CHUNK(CBASE)                                               \
        f32x4 acc0 = {0.f,0.f,0.f,0.f}, acc1 = acc0, acc2 = acc0, acc3 = acc0; \
        const int rbg = (CBASE) + 16 * wr + m + gp;                       \
        const int rb7 = (CBASE) + 16 * wr + m + 14;                       \
        { const int _Pb = 0; PPAIR(rbg +  0) }                            \
        { const int _Pb = 1; PPAIR(rbg +  2) }                            \
        { const int _Pb = 2; PPAIR(rbg +  4) }                            \
        { const int _Pb = 3; PPAIR(rbg +  6) }                            \
        { const int _Pb = 4; PPAIR(rbg +  8) }                            \
        { const int _Pb = 5; PPAIR(rbg + 10) }                            \
        { const int _Pb = 6; PPAIR(rbg + 12) }                            \
        { const int _Pb = 7; PPAIR(rb7) }                                 \
        const int ocb = c0 + 64 * wc + m;                                 \
        const int or0 = r0 + (CBASE) + 16 * wr + g * 4;                   \
        { STORE_TILE(0, acc0) STORE_TILE(1, acc1)                         \
          STORE_TILE(2, acc2) STORE_TILE(3, acc3) }

    #define STORE_TILE(t, a) {                                            \
        const int _oc = ocb + (t) * 16;                                   \
        if (_oc < N_OUT) {                                                \
            _Pragma("unroll")                                             \
            for (int r = 0; r < 4; ++r) {                                 \
                if (or0 + r < N_OUT)                                      \
                    out[(or0 + r) * N_OUT + _oc] = a[r] + b0;             \
            }                                                             \
        }                                                                 \
    }

    // ---- chunk 0: compute rows [0,64); stage rows [78,142) underneath ----
    {
        float4 s0 = make_float4(0.f,0.f,0.f,0.f), s1 = s0, s2 = s0, s3 = s0, s4 = s0;
        ISSUE_ITEM(78, tid,        s0);
        ISSUE_ITEM(78, tid +  512, s1);
        ISSUE_ITEM(78, tid + 1024, s2);
        ISSUE_ITEM(78, tid + 1536, s3);
        if (tid < CITEMS - 2048) ISSUE_ITEM(78, tid + 2048, s4);   // 256 tail

        DO_CHUNK(0)

        COMMIT_ITEM(78, tid,        s0);
        COMMIT_ITEM(78, tid +  512, s1);
        COMMIT_ITEM(78, tid + 1024, s2);
        COMMIT_ITEM(78, tid + 1536, s3);
        if (tid < CITEMS - 2048) COMMIT_ITEM(78, tid + 2048, s4);
        __syncthreads();
    }
    // ---- chunk 1: compute rows [64,128) ----
    {
        DO_CHUNK(64)
    }
    #undef PPAIR
    #undef DO_CHUNK
    #undef STORE_TILE
}

extern "C" void kernel_launch(void* const* d_in, const int* in_sizes, int n_in,
                              void* d_out, int out_size, void* d_ws, size_t ws_size,
                              hipStream_t stream) {
    const float* x    = (const float*)d_in[0];
    const float* w    = (const float*)d_in[1];
    const float* bias = (const float*)d_in[2];
    float* out        = (float*)d_out;
    unsigned short* bt = (unsigned short*)d_ws;     // 16 KB B-table

    btab_fill_kernel<<<dim3(16), dim3(64), 0, stream>>>(w, bt);

    dim3 block(512);
    dim3 grid(32 * 32);   // 1024 blocks, swizzled in-kernel; 3/CU resident
    Conv2DScratch_82025285419642_kernel<<<grid, block, 0, stream>>>(
        x, bt, bias, out);
}

// Round 16
// 38.777 us; speedup vs baseline: 1.2587x; 1.2345x over previous
//
#include <hip/hip_runtime.h>

#define N_IN   4096
#define N_OUT  4082      // 4096 - 15 + 1
#define KS     15
#define TM     128       // output rows per block (4 chunks x 32)
#define TN     256       // output cols per block
#define CH     32        // output rows per chunk (2 row-groups x 16)
#define NCH    4         // chunks per block
#define PR     142       // patch rows needed (TM + KS - 1)
#define PC     272       // patch cols staged (TN + 16)
#define PCB    (PC * 2)  // ring row pitch in bytes = 544
#define C4R    68        // float4 chunks per patch row (PC/4)
#define RING   96        // ring rows; per-chunk live span 78 < 96 -> alias-free
#define PITEMS (46 * C4R)          // prologue items (rows [0,46)) = 3128
#define CITEMS (CH * C4R)          // per-chunk staging items = 2176
#define RMOD(r) ((r) >= RING ? (r) - RING : (r))   // rows < 2*RING always
#define BTAB_U (16 * 64 * 8)       // B-table: 16 entries x 64 lanes x 8 bf16

// R16 = R11 (best measured: 35.4us) + 2-deep REGISTER DOUBLE-BUFFER of the
// per-pair fragment loads. R11's inner step was 7 ds_read_b128 -> 8 MFMAs
// with direct dependence (~120-200cyc LDS latency exposed per pair; MfmaUtil
// 14%, no pipe >35%). Now: L(P0) L(P1) C(P0) L(P2) C(P1) ... C(P7) — each
// pair's loads issued one full pair ahead, latency hidden under MFMAs.
// Frag sets f/g: 5 A + 2 B = 28 regs each, both sets static names (rule #20).
// Ledger: R11 measured 64 + 28 ~= 92 < 128 cap of (512,4). Occupancy arm is
// closed: (512,8)->VGPR 32, 48.8us; (512,6)->VGPR 40, 47.9us (starved).
// Spill gauge: WRITE_SIZE - 66.6 MB ~ 0 on dispatch 0.
// Bank: quad = (2*row + (g&1) + 2s) mod 8 -> 8 lanes/quad floor; wrap-safe
// (0 conflicts measured R11/R12). B table in LDS (lesson R4/5/7/8/10).

typedef __attribute__((ext_vector_type(8))) short bf16x8;
typedef __attribute__((ext_vector_type(4))) float f32x4;

__device__ inline unsigned short f2bf(float f) {   // round-to-nearest-even
    unsigned u = __builtin_bit_cast(unsigned, f);
    u += 0x7FFFu + ((u >> 16) & 1u);
    return (unsigned short)(u >> 16);
}
__device__ inline ushort4 f2bf4(float4 v) {
    ushort4 b; b.x = f2bf(v.x); b.y = f2bf(v.y); b.z = f2bf(v.z); b.w = f2bf(v.w);
    return b;
}

// load one staging item (patch row = base + it/C4R) into v, zero-padded
#define ISSUE_ITEM(base, it, v) {                                         \
    const int _row = (base) + (it) / C4R;                                 \
    const int _c4  = (it) % C4R;                                          \
    const int _gr  = r0 + _row;                                           \
    const int _gc  = c0 + _c4 * 4;                                        \
    if (_row < PR && _gr < N_IN && _gc < N_IN)                            \
        v = *reinterpret_cast<const float4*>(&x[_gr * N_IN + _gc]);       \
}
// convert + write item into its ring slot
#define COMMIT_ITEM(base, it, v) {                                        \
    const int _row = (base) + (it) / C4R;                                 \
    if (_row < PR) {                                                      \
        const int _ring = RMOD(_row);                                     \
        const int _c4   = (it) % C4R;                                     \
        *reinterpret_cast<ushort4*>(&xs[_ring * PC + _c4 * 4]) = f2bf4(v);\
    }                                                                     \
}

#define MF(a, b, c) __builtin_amdgcn_mfma_f32_16x16x32_bf16((a), (b), (c), 0, 0, 0)

__global__ __launch_bounds__(512, 4) void Conv2DScratch_82025285419642_kernel(
    const float* __restrict__ x, const float* __restrict__ w,
    const float* __restrict__ bias, float* __restrict__ out)
{
    __shared__ unsigned short xs[RING * PC + BTAB_U];   // ring + B table = 68,608 B

    const int tid  = threadIdx.x;
    const int lane = tid & 63;
    const int wv   = tid >> 6;
    const int m    = lane & 15;           // A row within band / D col
    const int g    = lane >> 4;           // k-group / D row group
    const int gp   = g >> 1;              // p' within pair
    const int g1   = g & 1;               // q' high/low 8
    const int wc   = wv & 3;              // col-group: cols [64wc, 64wc+64)
    const int wr   = wv >> 2;             // row-group: rows [32c+16wr, +16)

    // bijective XCD-chunked block swizzle (512 blocks, 8 XCDs, 64 each)
    const int bid = blockIdx.x;
    const int s   = ((bid & 7) << 6) | (bid >> 3);
    const int c0  = (s & 15) * TN;        // output col base
    const int r0  = (s >> 4) * TM;        // output row base

    // ---- prologue: stage rows [0,46); wave 0 builds B table while in flight ----
    float4 p0 = make_float4(0.f,0.f,0.f,0.f), p1 = p0, p2 = p0;
    ISSUE_ITEM(0, tid,        p0);
    ISSUE_ITEM(0, tid +  512, p1);
    ISSUE_ITEM(0, tid + 1024, p2);

    unsigned char* btb_w = (unsigned char*)&xs[RING * PC];
    if (wv == 0) {
        // entry (P,h): B[k=16p'+q'][n=m] = wpad[2P+p'][q' + 16h - n]
        #pragma unroll
        for (int P = 0; P < 8; ++P) {
            #pragma unroll
            for (int h = 0; h < 2; ++h) {
                bf16x8 f;
                #pragma unroll
                for (int e = 0; e < 8; ++e) {
                    const int prow = 2 * P + gp;
                    const int idx  = g1 * 8 + e + 16 * h - m;
                    const float vv = (prow < KS && idx >= 0 && idx < KS)
                                         ? w[prow * KS + idx] : 0.f;
                    f[e] = (short)f2bf(vv);
                }
                *reinterpret_cast<bf16x8*>(btb_w + (P * 2 + h) * 1024 + lane * 16) = f;
            }
        }
    }
    const float b0 = bias[0];

    COMMIT_ITEM(0, tid,        p0);
    COMMIT_ITEM(0, tid +  512, p1);
    COMMIT_ITEM(0, tid + 1024, p2);

    p0 = make_float4(0.f,0.f,0.f,0.f); p1 = p0; p2 = p0;
    ISSUE_ITEM(0, tid + 1536, p0);
    ISSUE_ITEM(0, tid + 2048, p1);
    ISSUE_ITEM(0, tid + 2560, p2);       // 2560+511 = 3071 < 3128: no guard
    COMMIT_ITEM(0, tid + 1536, p0);
    COMMIT_ITEM(0, tid + 2048, p1);
    COMMIT_ITEM(0, tid + 2560, p2);
    if (tid < PITEMS - 3072) {           // 56-item tail
        float4 pt = make_float4(0.f,0.f,0.f,0.f);
        ISSUE_ITEM(0, tid + 3072, pt);
        COMMIT_ITEM(0, tid + 3072, pt);
    }
    __syncthreads();

    const unsigned char* xsb = (const unsigned char*)xs;
    const unsigned char* btb = btb_w;
    const int cb0    = 128 * wc + 16 * g1;   // A-read byte offset within ring row
    const int lane16 = lane * 16;

    // fragment-set load (5 shared A-windows + 2 B-frags) and compute (8 MFMAs)
    #define LOADF(S, ROW, Pb) {                                           \
        const unsigned char* _ab = xsb + RMOD(ROW) * PCB + cb0;           \
        S##a0 = *reinterpret_cast<const bf16x8*>(_ab +   0);              \
        S##a1 = *reinterpret_cast<const bf16x8*>(_ab +  32);              \
        S##a2 = *reinterpret_cast<const bf16x8*>(_ab +  64);              \
        S##a3 = *reinterpret_cast<const bf16x8*>(_ab +  96);              \
        S##a4 = *reinterpret_cast<const bf16x8*>(_ab + 128);              \
        S##bl = *reinterpret_cast<const bf16x8*>(btb + (Pb) * 2048 + lane16);        \
        S##bh = *reinterpret_cast<const bf16x8*>(btb + (Pb) * 2048 + 1024 + lane16); \
    }
    #define COMPF(S) {                                                    \
        acc0 = MF(S##a0, S##bl, acc0); acc0 = MF(S##a1, S##bh, acc0);     \
        acc1 = MF(S##a1, S##bl, acc1); acc1 = MF(S##a2, S##bh, acc1);     \
        acc2 = MF(S##a2, S##bl, acc2); acc2 = MF(S##a3, S##bh, acc2);     \
        acc3 = MF(S##a3, S##bl, acc3); acc3 = MF(S##a4, S##bh, acc3);     \
    }

    // ---- ring loop: compute out rows [32c,32c+32), stage patch [32c+46,32c+78) ----
    for (int c = 0; c < NCH; ++c) {
        const int srow = 46 + c * CH;      // staging base row this chunk
        const int rbg  = c * CH + 16 * wr + m + gp;   // A row base (pairs 0-6)
        const int rb7  = c * CH + 16 * wr + m + 14;   // pair 7 (row 15 clamped)

        float4 s0 = make_float4(0.f,0.f,0.f,0.f), s1 = s0, s2 = s0;
        ISSUE_ITEM(srow, tid,        s0);
        ISSUE_ITEM(srow, tid +  512, s1);
        ISSUE_ITEM(srow, tid + 1024, s2);

        f32x4 acc0 = {0.f,0.f,0.f,0.f}, acc1 = acc0, acc2 = acc0, acc3 = acc0;
        bf16x8 fa0, fa1, fa2, fa3, fa4, fbl, fbh;
        bf16x8 ga0, ga1, ga2, ga3, ga4, gbl, gbh;

        LOADF(f, rbg +  0, 0)
        LOADF(g, rbg +  2, 1)
        COMPF(f)                      // P0; P1 loads in flight
        LOADF(f, rbg +  4, 2)
        COMPF(g)                      // P1
        LOADF(g, rbg +  6, 3)
        COMPF(f)                      // P2
        LOADF(f, rbg +  8, 4)
        COMPF(g)                      // P3

        COMMIT_ITEM(srow, tid,        s0);   // vmcnt cover: issued 4 pairs ago
        COMMIT_ITEM(srow, tid +  512, s1);
        COMMIT_ITEM(srow, tid + 1024, s2);
        s0 = make_float4(0.f,0.f,0.f,0.f); s1 = s0;
        ISSUE_ITEM(srow, tid + 1536, s0);
        if (tid < CITEMS - 2048) ISSUE_ITEM(srow, tid + 2048, s1);   // 128 tail

        LOADF(g, rbg + 10, 5)
        COMPF(f)                      // P4
        LOADF(f, rbg + 12, 6)
        COMPF(g)                      // P5
        LOADF(g, rb7,      7)
        COMPF(f)                      // P6

        COMMIT_ITEM(srow, tid + 1536, s0);
        if (tid < CITEMS - 2048) COMMIT_ITEM(srow, tid + 2048, s1);

        COMPF(g)                      // P7

        // stores: tile t cols [64wc+16t, +16); D: col = m, row = g*4 + r
        const int ocb = c0 + 64 * wc + m;
        const int or0 = r0 + c * CH + 16 * wr + g * 4;
        #define STORE_TILE(t, a) {                                        \
            const int _oc = ocb + (t) * 16;                               \
            if (_oc < N_OUT) {                                            \
                _Pragma("unroll")                                         \
                for (int r = 0; r < 4; ++r) {                             \
                    if (or0 + r < N_OUT)                                  \
                        out[(or0 + r) * N_OUT + _oc] = a[r] + b0;         \
                }                                                         \
            }                                                             \
        }
        STORE_TILE(0, acc0) STORE_TILE(1, acc1)
        STORE_TILE(2, acc2) STORE_TILE(3, acc3)
        #undef STORE_TILE

        __syncthreads();                   // staged rows visible for chunk c+1
    }
    #undef LOADF
    #undef COMPF
}

extern "C" void kernel_launch(void* const* d_in, const int* in_sizes, int n_in,
                              void* d_out, int out_size, void* d_ws, size_t ws_size,
                              hipStream_t stream) {
    const float* x    = (const float*)d_in[0];
    const float* w    = (const float*)d_in[1];
    const float* bias = (const float*)d_in[2];
    float* out        = (float*)d_out;

    dim3 block(512);
    dim3 grid(16 * 32);   // 512 blocks, swizzled in-kernel; 2/CU, all resident
    Conv2DScratch_82025285419642_kernel<<<grid, block, 0, stream>>>(x, w, bias, out);
}

// Round 17
// 38.684 us; speedup vs baseline: 1.2617x; 1.0024x over previous
//
#include <hip/hip_runtime.h>

#define N_IN   4096
#define N_OUT  4082      // 4096 - 15 + 1
#define KS     15
#define TM     128       // output rows per block (4 chunks x 32)
#define TN     256       // output cols per block
#define CH     32        // output rows per chunk (2 row-groups x 16)
#define NCH    4         // chunks per block
#define PR     142       // patch rows needed (TM + KS - 1)
#define PC     272       // patch cols staged (TN + 16)
#define PCB    (PC * 2)  // ring row pitch in bytes = 544
#define C4R    68        // float4 chunks per patch row (PC/4)
#define RING   96        // ring rows; per-chunk live span 78 < 96 -> alias-free
#define PITEMS (46 * C4R)          // prologue items (rows [0,46)) = 3128
#define CITEMS (CH * C4R)          // per-chunk staging items = 2176
#define RMOD(r) ((r) >= RING ? (r) - RING : (r))   // rows < 2*RING always
#define BTAB_U (16 * 64 * 8)       // B-table: 16 entries x 64 lanes x 8 bf16

// R17 = R16 + amdgpu_waves_per_eu(4,4). R16's frag double-buffer was defeated:
// allocator CHOSE 64 VGPR (targeting 8 waves/EU occupancy) and spilled the
// second frag set (WRITE 70.7MB, dur regressed). Pinning max waves/EU = 4
// removes the occupancy incentive -> allocator free to use the true demand
// (~107 <= 128 cap) with zero spill. Body identical to R16: pipeline
// L(P0) L(P1) C(P0) L(P2) C(P1) ... C(P7); frag sets f/g = 28 regs each.
// Decisive check: VGPR_Count must rise to ~96-128; WRITE back to ~66.6 MB.
// If VGPR stays 64: hipcc won't allocate past 64 at 512 threads -> structure
// plateau is R11's 35.4us.
// Bank: quad = (2*row + (g&1) + 2s) mod 8 -> 8 lanes/quad floor; wrap-safe
// (0 conflicts measured). B table in LDS (lesson R4/5/7/8/10).

typedef __attribute__((ext_vector_type(8))) short bf16x8;
typedef __attribute__((ext_vector_type(4))) float f32x4;

__device__ inline unsigned short f2bf(float f) {   // round-to-nearest-even
    unsigned u = __builtin_bit_cast(unsigned, f);
    u += 0x7FFFu + ((u >> 16) & 1u);
    return (unsigned short)(u >> 16);
}
__device__ inline ushort4 f2bf4(float4 v) {
    ushort4 b; b.x = f2bf(v.x); b.y = f2bf(v.y); b.z = f2bf(v.z); b.w = f2bf(v.w);
    return b;
}

// load one staging item (patch row = base + it/C4R) into v, zero-padded
#define ISSUE_ITEM(base, it, v) {                                         \
    const int _row = (base) + (it) / C4R;                                 \
    const int _c4  = (it) % C4R;                                          \
    const int _gr  = r0 + _row;                                           \
    const int _gc  = c0 + _c4 * 4;                                        \
    if (_row < PR && _gr < N_IN && _gc < N_IN)                            \
        v = *reinterpret_cast<const float4*>(&x[_gr * N_IN + _gc]);       \
}
// convert + write item into its ring slot
#define COMMIT_ITEM(base, it, v) {                                        \
    const int _row = (base) + (it) / C4R;                                 \
    if (_row < PR) {                                                      \
        const int _ring = RMOD(_row);                                     \
        const int _c4   = (it) % C4R;                                     \
        *reinterpret_cast<ushort4*>(&xs[_ring * PC + _c4 * 4]) = f2bf4(v);\
    }                                                                     \
}

#define MF(a, b, c) __builtin_amdgcn_mfma_f32_16x16x32_bf16((a), (b), (c), 0, 0, 0)

__global__ __launch_bounds__(512, 4)
__attribute__((amdgpu_waves_per_eu(4, 4)))
void Conv2DScratch_82025285419642_kernel(
    const float* __restrict__ x, const float* __restrict__ w,
    const float* __restrict__ bias, float* __restrict__ out)
{
    __shared__ unsigned short xs[RING * PC + BTAB_U];   // ring + B table = 68,608 B

    const int tid  = threadIdx.x;
    const int lane = tid & 63;
    const int wv   = tid >> 6;
    const int m    = lane & 15;           // A row within band / D col
    const int g    = lane >> 4;           // k-group / D row group
    const int gp   = g >> 1;              // p' within pair
    const int g1   = g & 1;               // q' high/low 8
    const int wc   = wv & 3;              // col-group: cols [64wc, 64wc+64)
    const int wr   = wv >> 2;             // row-group: rows [32c+16wr, +16)

    // bijective XCD-chunked block swizzle (512 blocks, 8 XCDs, 64 each)
    const int bid = blockIdx.x;
    const int s   = ((bid & 7) << 6) | (bid >> 3);
    const int c0  = (s & 15) * TN;        // output col base
    const int r0  = (s >> 4) * TM;        // output row base

    // ---- prologue: stage rows [0,46); wave 0 builds B table while in flight ----
    float4 p0 = make_float4(0.f,0.f,0.f,0.f), p1 = p0, p2 = p0;
    ISSUE_ITEM(0, tid,        p0);
    ISSUE_ITEM(0, tid +  512, p1);
    ISSUE_ITEM(0, tid + 1024, p2);

    unsigned char* btb_w = (unsigned char*)&xs[RING * PC];
    if (wv == 0) {
        // entry (P,h): B[k=16p'+q'][n=m] = wpad[2P+p'][q' + 16h - n]
        #pragma unroll
        for (int P = 0; P < 8; ++P) {
            #pragma unroll
            for (int h = 0; h < 2; ++h) {
                bf16x8 f;
                #pragma unroll
                for (int e = 0; e < 8; ++e) {
                    const int prow = 2 * P + gp;
                    const int idx  = g1 * 8 + e + 16 * h - m;
                    const float vv = (prow < KS && idx >= 0 && idx < KS)
                                         ? w[prow * KS + idx] : 0.f;
                    f[e] = (short)f2bf(vv);
                }
                *reinterpret_cast<bf16x8*>(btb_w + (P * 2 + h) * 1024 + lane * 16) = f;
            }
        }
    }
    const float b0 = bias[0];

    COMMIT_ITEM(0, tid,        p0);
    COMMIT_ITEM(0, tid +  512, p1);
    COMMIT_ITEM(0, tid + 1024, p2);

    p0 = make_float4(0.f,0.f,0.f,0.f); p1 = p0; p2 = p0;
    ISSUE_ITEM(0, tid + 1536, p0);
    ISSUE_ITEM(0, tid + 2048, p1);
    ISSUE_ITEM(0, tid + 2560, p2);       // 2560+511 = 3071 < 3128: no guard
    COMMIT_ITEM(0, tid + 1536, p0);
    COMMIT_ITEM(0, tid + 2048, p1);
    COMMIT_ITEM(0, tid + 2560, p2);
    if (tid < PITEMS - 3072) {           // 56-item tail
        float4 pt = make_float4(0.f,0.f,0.f,0.f);
        ISSUE_ITEM(0, tid + 3072, pt);
        COMMIT_ITEM(0, tid + 3072, pt);
    }
    __syncthreads();

    const unsigned char* xsb = (const unsigned char*)xs;
    const unsigned char* btb = btb_w;
    const int cb0    = 128 * wc + 16 * g1;   // A-read byte offset within ring row
    const int lane16 = lane * 16;

    // fragment-set load (5 shared A-windows + 2 B-frags) and compute (8 MFMAs)
    #define LOADF(S, ROW, Pb) {                                           \
        const unsigned char* _ab = xsb + RMOD(ROW) * PCB + cb0;           \
        S##a0 = *reinterpret_cast<const bf16x8*>(_ab +   0);              \
        S##a1 = *reinterpret_cast<const bf16x8*>(_ab +  32);              \
        S##a2 = *reinterpret_cast<const bf16x8*>(_ab +  64);              \
        S##a3 = *reinterpret_cast<const bf16x8*>(_ab +  96);              \
        S##a4 = *reinterpret_cast<const bf16x8*>(_ab + 128);              \
        S##bl = *reinterpret_cast<const bf16x8*>(btb + (Pb) * 2048 + lane16);        \
        S##bh = *reinterpret_cast<const bf16x8*>(btb + (Pb) * 2048 + 1024 + lane16); \
    }
    #define COMPF(S) {                                                    \
        acc0 = MF(S##a0, S##bl, acc0); acc0 = MF(S##a1, S##bh, acc0);     \
        acc1 = MF(S##a1, S##bl, acc1); acc1 = MF(S##a2, S##bh, acc1);     \
        acc2 = MF(S##a2, S##bl, acc2); acc2 = MF(S##a3, S##bh, acc2);     \
        acc3 = MF(S##a3, S##bl, acc3); acc3 = MF(S##a4, S##bh, acc3);     \
    }

    // ---- ring loop: compute out rows [32c,32c+32), stage patch [32c+46,32c+78) ----
    for (int c = 0; c < NCH; ++c) {
        const int srow = 46 + c * CH;      // staging base row this chunk
        const int rbg  = c * CH + 16 * wr + m + gp;   // A row base (pairs 0-6)
        const int rb7  = c * CH + 16 * wr + m + 14;   // pair 7 (row 15 clamped)

        float4 s0 = make_float4(0.f,0.f,0.f,0.f), s1 = s0, s2 = s0;
        ISSUE_ITEM(srow, tid,        s0);
        ISSUE_ITEM(srow, tid +  512, s1);
        ISSUE_ITEM(srow, tid + 1024, s2);

        f32x4 acc0 = {0.f,0.f,0.f,0.f}, acc1 = acc0, acc2 = acc0, acc3 = acc0;
        bf16x8 fa0, fa1, fa2, fa3, fa4, fbl, fbh;
        bf16x8 ga0, ga1, ga2, ga3, ga4, gbl, gbh;

        LOADF(f, rbg +  0, 0)
        LOADF(g, rbg +  2, 1)
        COMPF(f)                      // P0; P1 loads in flight
        LOADF(f, rbg +  4, 2)
        COMPF(g)                      // P1
        LOADF(g, rbg +  6, 3)
        COMPF(f)                      // P2
        LOADF(f, rbg +  8, 4)
        COMPF(g)                      // P3

        COMMIT_ITEM(srow, tid,        s0);   // vmcnt cover: issued 4 pairs ago
        COMMIT_ITEM(srow, tid +  512, s1);
        COMMIT_ITEM(srow, tid + 1024, s2);
        s0 = make_float4(0.f,0.f,0.f,0.f); s1 = s0;
        ISSUE_ITEM(srow, tid + 1536, s0);
        if (tid < CITEMS - 2048) ISSUE_ITEM(srow, tid + 2048, s1);   // 128 tail

        LOADF(g, rbg + 10, 5)
        COMPF(f)                      // P4
        LOADF(f, rbg + 12, 6)
        COMPF(g)                      // P5
        LOADF(g, rb7,      7)
        COMPF(f)                      // P6

        COMMIT_ITEM(srow, tid + 1536, s0);
        if (tid < CITEMS - 2048) COMMIT_ITEM(srow, tid + 2048, s1);

        COMPF(g)                      // P7

        // stores: tile t cols [64wc+16t, +16); D: col = m, row = g*4 + r
        const int ocb = c0 + 64 * wc + m;
        const int or0 = r0 + c * CH + 16 * wr + g * 4;
        #define STORE_TILE(t, a) {                                        \
            const int _oc = ocb + (t) * 16;                               \
            if (_oc < N_OUT) {                                            \
                _Pragma("unroll")                                         \
                for (int r = 0; r < 4; ++r) {                             \
                    if (or0 + r < N_OUT)                                  \
                        out[(or0 + r) * N_OUT + _oc] = a[r] + b0;         \
                }                                                         \
            }                                                             \
        }
        STORE_TILE(0, acc0) STORE_TILE(1, acc1)
        STORE_TILE(2, acc2) STORE_TILE(3, acc3)
        #undef STORE_TILE

        __syncthreads();                   // staged rows visible for chunk c+1
    }
    #undef LOADF
    #undef COMPF
}

extern "C" void kernel_launch(void* const* d_in, const int* in_sizes, int n_in,
                              void* d_out, int out_size, void* d_ws, size_t ws_size,
                              hipStream_t stream) {
    const float* x    = (const float*)d_in[0];
    const float* w    = (const float*)d_in[1];
    const float* bias = (const float*)d_in[2];
    float* out        = (float*)d_out;

    dim3 block(512);
    dim3 grid(16 * 32);   // 512 blocks, swizzled in-kernel; 2/CU, all resident
    Conv2DScratch_82025285419642_kernel<<<grid, block, 0, stream>>>(x, w, bias, out);
}